// Round 1
// baseline (5580.476 us; speedup 1.0000x reference)
//
#include <hip/hip_runtime.h>
#include <hip/hip_bf16.h>

typedef __attribute__((ext_vector_type(8))) short bf16x8;
typedef __attribute__((ext_vector_type(4))) float f32x4;

#define SEQT 2048
#define BATCH 32
#define INDIM 512
#define EMB 256
#define HHX 128
#define LBL 16

__device__ __forceinline__ unsigned short f2bf(float f) {
    unsigned u = __float_as_uint(f);
    u += 0x7FFFu + ((u >> 16) & 1u);
    return (unsigned short)(u >> 16);
}
__device__ __forceinline__ float bf2f(unsigned short s) {
    return __uint_as_float(((unsigned)s) << 16);
}
__device__ __forceinline__ float sigm(float x) { return 1.0f / (1.0f + __expf(-x)); }
__device__ __forceinline__ float tanh_(float x) { return 1.0f - 2.0f / (1.0f + __expf(2.0f * x)); }

// Gate-row permutation: g' = w*64 + q*16 + r  <->  orig = q*128 + w*16 + r
__device__ __forceinline__ int orig_of(int gp) {
    return ((gp >> 4) & 3) * 128 + (gp >> 6) * 16 + (gp & 15);
}

// ---------------- prep: combined W (Wih @ in_W) + bias, permuted rows ----------------
__global__ __launch_bounds__(256) void k_prep_wc(
    const float* __restrict__ in_W, const float* __restrict__ in_b,
    const float* __restrict__ Wih_f, const float* __restrict__ b_f,
    const float* __restrict__ Wih_b, const float* __restrict__ b_b,
    unsigned short* __restrict__ Wc, float* __restrict__ bc)
{
    int G = blockIdx.x;              // 0..1023
    int dir = G >> 9, gp = G & 511;
    int orig = orig_of(gp);
    const float* Wih = dir ? Wih_b : Wih_f;
    const float* bias = dir ? b_b : b_f;
    __shared__ float wrow[EMB];
    int tid = threadIdx.x;
    for (int e = tid; e < EMB; e += 256) wrow[e] = Wih[orig * EMB + e];
    __syncthreads();
    for (int k = tid; k < INDIM; k += 256) {
        float acc = 0.f;
        #pragma unroll 4
        for (int e = 0; e < EMB; ++e) acc += wrow[e] * in_W[e * INDIM + k];
        Wc[(size_t)G * INDIM + k] = f2bf(acc);
    }
    if (tid < 64) {
        float p = 0.f;
        for (int e = tid; e < EMB; e += 64) p += wrow[e] * in_b[e];
        for (int off = 32; off; off >>= 1) p += __shfl_xor(p, off);
        if (tid == 0) bc[G] = bias[orig] + p;
    }
}

// ---------------- prep: bf16 converts (Whh permuted, out_W) ----------------
__global__ __launch_bounds__(256) void k_prep_misc(
    const float* __restrict__ Whh_f, const float* __restrict__ Whh_b,
    const float* __restrict__ out_W,
    unsigned short* __restrict__ Whh_bf, unsigned short* __restrict__ outW_bf)
{
    int idx = blockIdx.x * 256 + threadIdx.x;
    int stride = gridDim.x * 256;
    for (int i = idx; i < 1024 * HHX; i += stride) {
        int G = i >> 7, k = i & 127;
        int dir = G >> 9, gp = G & 511;
        int orig = orig_of(gp);
        const float* Whh = dir ? Whh_b : Whh_f;
        Whh_bf[i] = f2bf(Whh[orig * HHX + k]);
    }
    for (int i = idx; i < LBL * 256; i += stride) outW_bf[i] = f2bf(out_W[i]);
}

// ---------------- big GEMM: P(65536 x 1024) = S @ Wc^T + bc ----------------
// BM=64 BN=256 BK=64, 512 threads (8 waves, 2x4), in-kernel fp32->bf16 A convert.
__global__ __launch_bounds__(512) void k_gemm_p(
    const float* __restrict__ S, const unsigned short* __restrict__ Wc,
    const float* __restrict__ bc, unsigned short* __restrict__ P)
{
    int m0 = blockIdx.y * 64;
    int n0 = blockIdx.x * 256;
    int tid = threadIdx.x;
    int w = tid >> 6, l = tid & 63;
    int lr = l & 15, lq = l >> 4;
    int wm = w >> 2, wn = w & 3;

    __shared__ __align__(16) unsigned short Alds[64 * 64];
    __shared__ __align__(16) unsigned short Blds[256 * 64];

    const f32x4 fzero = {0.f, 0.f, 0.f, 0.f};
    f32x4 acc[2][4];
    #pragma unroll
    for (int a = 0; a < 2; ++a)
        #pragma unroll
        for (int b = 0; b < 4; ++b) acc[a][b] = fzero;

    for (int kt = 0; kt < 8; ++kt) {
        { // stage A (convert fp32->bf16, XOR-swizzled rows of 128B)
            int r = tid >> 3, c = tid & 7;
            const float* src = S + (size_t)(m0 + r) * INDIM + kt * 64 + c * 8;
            float4 v0 = *(const float4*)src;
            float4 v1 = *(const float4*)(src + 4);
            bf16x8 wv;
            wv[0] = (short)f2bf(v0.x); wv[1] = (short)f2bf(v0.y);
            wv[2] = (short)f2bf(v0.z); wv[3] = (short)f2bf(v0.w);
            wv[4] = (short)f2bf(v1.x); wv[5] = (short)f2bf(v1.y);
            wv[6] = (short)f2bf(v1.z); wv[7] = (short)f2bf(v1.w);
            *(bf16x8*)((char*)Alds + r * 128 + ((c * 16) ^ ((r & 7) << 4))) = wv;
        }
        { // stage B
            int r = tid >> 1, h = tid & 1;
            const unsigned short* bs = Wc + (size_t)(n0 + r) * INDIM + kt * 64;
            #pragma unroll
            for (int cc = 0; cc < 4; ++cc) {
                int ch = h * 4 + cc;
                bf16x8 v = *(const bf16x8*)(bs + ch * 8);
                *(bf16x8*)((char*)Blds + r * 128 + ((ch * 16) ^ ((r & 7) << 4))) = v;
            }
        }
        __syncthreads();
        bf16x8 af[2][2], bfv[4][2];
        #pragma unroll
        for (int tm = 0; tm < 2; ++tm)
            #pragma unroll
            for (int kk = 0; kk < 2; ++kk) {
                int ra = wm * 32 + tm * 16 + lr;
                af[tm][kk] = *(const bf16x8*)((char*)Alds + ra * 128 + ((kk * 64 + lq * 16) ^ ((ra & 7) << 4)));
            }
        #pragma unroll
        for (int tn = 0; tn < 4; ++tn)
            #pragma unroll
            for (int kk = 0; kk < 2; ++kk) {
                int rb = wn * 64 + tn * 16 + lr;
                bfv[tn][kk] = *(const bf16x8*)((char*)Blds + rb * 128 + ((kk * 64 + lq * 16) ^ ((rb & 7) << 4)));
            }
        #pragma unroll
        for (int tm = 0; tm < 2; ++tm)
            #pragma unroll
            for (int tn = 0; tn < 4; ++tn)
                #pragma unroll
                for (int kk = 0; kk < 2; ++kk)
                    acc[tm][tn] = __builtin_amdgcn_mfma_f32_16x16x32_bf16(af[tm][kk], bfv[tn][kk], acc[tm][tn], 0, 0, 0);
        __syncthreads();
    }
    #pragma unroll
    for (int tn = 0; tn < 4; ++tn) {
        int n = n0 + wn * 64 + tn * 16 + lr;
        float bias = bc[n];
        #pragma unroll
        for (int tm = 0; tm < 2; ++tm) {
            #pragma unroll
            for (int j = 0; j < 4; ++j) {
                int m = m0 + wm * 32 + tm * 16 + lq * 4 + j;
                P[(size_t)m * 1024 + n] = f2bf(acc[tm][tn][j] + bias);
            }
        }
    }
}

// ---------------- LSTM recurrence: 4 blocks (dir x batch-tile), 512 threads ----------------
// Whh fragments in registers; h exchanged through 4KB double-buffered swizzled LDS.
__global__ __launch_bounds__(512) void k_lstm(
    const unsigned short* __restrict__ P, const unsigned short* __restrict__ Whh_bf,
    const float* __restrict__ h0, const float* __restrict__ c0,
    unsigned short* __restrict__ H)
{
    int blk = blockIdx.x;
    int dir = blk >> 1, bt = blk & 1;
    int tid = threadIdx.x;
    int w = tid >> 6, l = tid & 63;
    int lr = l & 15, lq = l >> 4;

    __shared__ __align__(16) unsigned short hbuf[2][16 * 128];

    // Whh fragments: wave w owns gates q=0..3 of units [w*16, w*16+16)
    bf16x8 bfrag[4][4];
    #pragma unroll
    for (int q = 0; q < 4; ++q)
        #pragma unroll
        for (int ko = 0; ko < 4; ++ko) {
            int row = dir * 512 + w * 64 + q * 16 + lr;
            bfrag[q][ko] = *(const bf16x8*)(Whh_bf + (size_t)row * HHX + ko * 32 + lq * 8);
        }

    float c_reg[4];
    #pragma unroll
    for (int j = 0; j < 4; ++j)
        c_reg[j] = c0[(dir * 32 + bt * 16 + lq * 4 + j) * HHX + w * 16 + lr];

    for (int e = tid; e < 2048; e += 512) {
        int b = e >> 7, u = e & 127;
        float hv = h0[(dir * 32 + bt * 16 + b) * HHX + u];
        *(unsigned short*)((char*)hbuf[0] + ((b * 256 + u * 2) ^ ((b & 7) << 4))) = f2bf(hv);
    }
    __syncthreads();

    int baseP_col = dir * 512 + w * 64 + lr;
    unsigned short pc[16], pn[16];
    int t0 = dir ? (SEQT - 1) : 0;
    #pragma unroll
    for (int q = 0; q < 4; ++q)
        #pragma unroll
        for (int j = 0; j < 4; ++j)
            pc[q * 4 + j] = P[(size_t)(t0 * 32 + bt * 16 + lq * 4 + j) * 1024 + baseP_col + q * 16];

    int cur = 0;
    for (int tt = 0; tt < SEQT; ++tt) {
        int t = dir ? (SEQT - 1 - tt) : tt;
        int tnext = dir ? (t - 1) : (t + 1);
        if (tt + 1 < SEQT) {
            #pragma unroll
            for (int q = 0; q < 4; ++q)
                #pragma unroll
                for (int j = 0; j < 4; ++j)
                    pn[q * 4 + j] = P[(size_t)(tnext * 32 + bt * 16 + lq * 4 + j) * 1024 + baseP_col + q * 16];
        }
        bf16x8 af[4];
        #pragma unroll
        for (int ko = 0; ko < 4; ++ko)
            af[ko] = *(const bf16x8*)((char*)hbuf[cur] + ((lr * 256 + ko * 64 + lq * 16) ^ ((lr & 7) << 4)));
        f32x4 acc[4];
        #pragma unroll
        for (int q = 0; q < 4; ++q) {
            f32x4 a = {0.f, 0.f, 0.f, 0.f};
            #pragma unroll
            for (int ko = 0; ko < 4; ++ko)
                a = __builtin_amdgcn_mfma_f32_16x16x32_bf16(af[ko], bfrag[q][ko], a, 0, 0, 0);
            acc[q] = a;
        }
        float hn[4];
        #pragma unroll
        for (int j = 0; j < 4; ++j) {
            float ig = acc[0][j] + bf2f(pc[0 * 4 + j]);
            float fg = acc[1][j] + bf2f(pc[1 * 4 + j]);
            float gg = acc[2][j] + bf2f(pc[2 * 4 + j]);
            float og = acc[3][j] + bf2f(pc[3 * 4 + j]);
            float cn = sigm(fg) * c_reg[j] + sigm(ig) * tanh_(gg);
            c_reg[j] = cn;
            hn[j] = sigm(og) * tanh_(cn);
        }
        #pragma unroll
        for (int j = 0; j < 4; ++j) {
            int b = lq * 4 + j, u = w * 16 + lr;
            unsigned short hb = f2bf(hn[j]);
            *(unsigned short*)((char*)hbuf[cur ^ 1] + ((b * 256 + u * 2) ^ ((b & 7) << 4))) = hb;
            H[(size_t)(t * 32 + bt * 16 + b) * 256 + dir * 128 + u] = hb;
        }
        #pragma unroll
        for (int i = 0; i < 16; ++i) pc[i] = pn[i];
        cur ^= 1;
        __syncthreads();
    }
}

// ---------------- feats: F(65536x16) = H @ outW^T + out_b ----------------
__global__ __launch_bounds__(256) void k_feats(
    const unsigned short* __restrict__ H, const unsigned short* __restrict__ outW_bf,
    const float* __restrict__ out_b, float* __restrict__ feats)
{
    int m0 = blockIdx.x * 64;
    int tid = threadIdx.x;
    int w = tid >> 6, l = tid & 63;
    int lr = l & 15, lq = l >> 4;
    __shared__ __align__(16) unsigned short Hl[64 * 256];

    {
        int r = tid >> 2, cb = (tid & 3) * 8;
        #pragma unroll
        for (int cc = 0; cc < 8; ++cc) {
            int c = cb + cc;
            bf16x8 v = *(const bf16x8*)(H + (size_t)(m0 + r) * 256 + c * 8);
            *(bf16x8*)((char*)Hl + r * 512 + ((c * 16) ^ ((r & 7) << 4))) = v;
        }
    }
    bf16x8 bw[8];
    #pragma unroll
    for (int ko = 0; ko < 8; ++ko)
        bw[ko] = *(const bf16x8*)(outW_bf + lr * 256 + ko * 32 + lq * 8);
    __syncthreads();
    int row = w * 16 + lr;
    f32x4 acc = {0.f, 0.f, 0.f, 0.f};
    #pragma unroll
    for (int ko = 0; ko < 8; ++ko) {
        bf16x8 a = *(const bf16x8*)((char*)Hl + row * 512 + ((ko * 64 + lq * 16) ^ ((row & 7) << 4)));
        acc = __builtin_amdgcn_mfma_f32_16x16x32_bf16(a, bw[ko], acc, 0, 0, 0);
    }
    float ob = out_b[lr];
    #pragma unroll
    for (int j = 0; j < 4; ++j) {
        int m = m0 + w * 16 + lq * 4 + j;
        feats[(size_t)m * 16 + lr] = acc[j] + ob;
    }
}

// ---------------- Viterbi: 1 block per batch, 1 wave ----------------
__global__ __launch_bounds__(64) void k_viterbi(
    const float* __restrict__ feats, const float* __restrict__ trans,
    float* __restrict__ out)
{
    int b = blockIdx.x;
    int l = threadIdx.x;
    int i = l >> 2, s = l & 3;
    __shared__ unsigned char bp[SEQT * 16];
    __shared__ __align__(16) float fch[256 * 16];

    float tr[4];
    #pragma unroll
    for (int m = 0; m < 4; ++m) tr[m] = trans[i * 16 + s * 4 + m];
    float fv[16];
    #pragma unroll
    for (int j = 0; j < 16; ++j) fv[j] = (j == 0) ? 0.f : -10000.f;

    for (int t = 0; t < SEQT; ++t) {
        if ((t & 255) == 0) {
            __syncthreads();
            for (int k = l; k < 256; k += 64) {
                const float4* src = (const float4*)(feats + (size_t)((t + k) * 32 + b) * 16);
                float4 v0 = src[0], v1 = src[1], v2 = src[2], v3 = src[3];
                float4* dst = (float4*)(fch + k * 16);
                dst[0] = v0; dst[1] = v1; dst[2] = v2; dst[3] = v3;
            }
            __syncthreads();
        }
        float best = fv[s * 4] + tr[0];
        int bj = s * 4;
        #pragma unroll
        for (int m = 1; m < 4; ++m) {
            float v = fv[s * 4 + m] + tr[m];
            if (v > best) { best = v; bj = s * 4 + m; }
        }
        #pragma unroll
        for (int off = 1; off <= 2; off <<= 1) {
            float ov = __shfl_xor(best, off);
            int oj = __shfl_xor(bj, off);
            if (ov > best || (ov == best && oj < bj)) { best = ov; bj = oj; }
        }
        float fvn = best + fch[(t & 255) * 16 + i];
        if (s == 0) bp[t * 16 + i] = (unsigned char)bj;
        #pragma unroll
        for (int jj = 0; jj < 16; ++jj) fv[jj] = __shfl(fvn, jj * 4);
    }
    float bestS = fv[0] + trans[16 + 0];
    int bl = 0;
    #pragma unroll
    for (int jj = 1; jj < 16; ++jj) {
        float tv = fv[jj] + trans[16 + jj];
        if (tv > bestS) { bestS = tv; bl = jj; }
    }
    __syncthreads();
    if (l == 0) {
        out[b] = bestS;
        int lbl = bl;
        for (int t = SEQT - 1; t >= 0; --t) {
            out[32 + (size_t)t * 32 + b] = (float)lbl;
            lbl = bp[t * 16 + lbl];
        }
    }
}

extern "C" void kernel_launch(void* const* d_in, const int* in_sizes, int n_in,
                              void* d_out, int out_size, void* d_ws, size_t ws_size,
                              hipStream_t stream) {
    const float* source = (const float*)d_in[0];
    const float* in_W  = (const float*)d_in[1];
    const float* in_b  = (const float*)d_in[2];
    const float* Wih_f = (const float*)d_in[3];
    const float* Whh_f = (const float*)d_in[4];
    const float* b_f   = (const float*)d_in[5];
    const float* Wih_b = (const float*)d_in[6];
    const float* Whh_b = (const float*)d_in[7];
    const float* b_b   = (const float*)d_in[8];
    const float* out_W = (const float*)d_in[9];
    const float* out_b = (const float*)d_in[10];
    const float* trans = (const float*)d_in[11];
    const float* h0    = (const float*)d_in[12];
    const float* c0    = (const float*)d_in[13];
    float* out = (float*)d_out;

    char* ws = (char*)d_ws;
    unsigned short* P       = (unsigned short*)(ws);                 // 65536*1024*2 = 134217728
    unsigned short* H       = (unsigned short*)(ws + 134217728);     // 65536*256*2  =  33554432
    float*          feats   = (float*)         (ws + 167772160);     // 65536*16*4   =   4194304
    unsigned short* Wc      = (unsigned short*)(ws + 171966464);     // 1024*512*2   =   1048576
    float*          bc      = (float*)         (ws + 173015040);     // 1024*4
    unsigned short* Whh_bf  = (unsigned short*)(ws + 173019136);     // 1024*128*2   =    262144
    unsigned short* outW_bf = (unsigned short*)(ws + 173281280);     // 16*256*2
    // total ~173.3 MB

    hipLaunchKernelGGL(k_prep_wc, dim3(1024), dim3(256), 0, stream,
                       in_W, in_b, Wih_f, b_f, Wih_b, b_b, Wc, bc);
    hipLaunchKernelGGL(k_prep_misc, dim3(256), dim3(256), 0, stream,
                       Whh_f, Whh_b, out_W, Whh_bf, outW_bf);
    hipLaunchKernelGGL(k_gemm_p, dim3(4, 1024), dim3(512), 0, stream,
                       source, Wc, bc, P);
    hipLaunchKernelGGL(k_lstm, dim3(4), dim3(512), 0, stream,
                       P, Whh_bf, h0, c0, H);
    hipLaunchKernelGGL(k_feats, dim3(1024), dim3(256), 0, stream,
                       H, outW_bf, out_b, feats);
    hipLaunchKernelGGL(k_viterbi, dim3(32), dim3(64), 0, stream,
                       feats, trans, out);
}

// Round 2
// 2830.952 us; speedup vs baseline: 1.9712x; 1.9712x over previous
//
#include <hip/hip_runtime.h>
#include <hip/hip_bf16.h>

typedef __attribute__((ext_vector_type(8))) short bf16x8;
typedef __attribute__((ext_vector_type(4))) float f32x4;

#define SEQT 2048
#define BATCH 32
#define INDIM 512
#define EMB 256
#define HHX 128
#define LBL 16
#define LOG2E 1.44269504f

__device__ __forceinline__ unsigned short f2bf(float f) {
    unsigned u = __float_as_uint(f);
    u += 0x7FFFu + ((u >> 16) & 1u);
    return (unsigned short)(u >> 16);
}
__device__ __forceinline__ float bf2f(unsigned short s) {
    return __uint_as_float(((unsigned)s) << 16);
}
// fast, saturation-safe: x->+inf => 1, x->-inf => 0
__device__ __forceinline__ float sigm(float x) {
    return __builtin_amdgcn_rcpf(1.0f + __builtin_amdgcn_exp2f(-LOG2E * x));
}
// x->+inf => 1, x->-inf => -1 (1 - 2/(1+e^{2x}) form avoids inf*0)
__device__ __forceinline__ float tanh_(float x) {
    return 1.0f - 2.0f * __builtin_amdgcn_rcpf(1.0f + __builtin_amdgcn_exp2f(2.0f * LOG2E * x));
}

// Gate-row permutation: g' = w*64 + q*16 + r  <->  orig = q*128 + w*16 + r
__device__ __forceinline__ int orig_of(int gp) {
    return ((gp >> 4) & 3) * 128 + (gp >> 6) * 16 + (gp & 15);
}

// ---------------- prep: combined W (Wih @ in_W) + bias, permuted rows ----------------
__global__ __launch_bounds__(256) void k_prep_wc(
    const float* __restrict__ in_W, const float* __restrict__ in_b,
    const float* __restrict__ Wih_f, const float* __restrict__ b_f,
    const float* __restrict__ Wih_b, const float* __restrict__ b_b,
    unsigned short* __restrict__ Wc, float* __restrict__ bc)
{
    int G = blockIdx.x;              // 0..1023
    int dir = G >> 9, gp = G & 511;
    int orig = orig_of(gp);
    const float* Wih = dir ? Wih_b : Wih_f;
    const float* bias = dir ? b_b : b_f;
    __shared__ float wrow[EMB];
    int tid = threadIdx.x;
    for (int e = tid; e < EMB; e += 256) wrow[e] = Wih[orig * EMB + e];
    __syncthreads();
    for (int k = tid; k < INDIM; k += 256) {
        float acc = 0.f;
        #pragma unroll 4
        for (int e = 0; e < EMB; ++e) acc += wrow[e] * in_W[e * INDIM + k];
        Wc[(size_t)G * INDIM + k] = f2bf(acc);
    }
    if (tid < 64) {
        float p = 0.f;
        for (int e = tid; e < EMB; e += 64) p += wrow[e] * in_b[e];
        for (int off = 32; off; off >>= 1) p += __shfl_xor(p, off);
        if (tid == 0) bc[G] = bias[orig] + p;
    }
}

// ---------------- prep: bf16 converts (Whh permuted, out_W) ----------------
__global__ __launch_bounds__(256) void k_prep_misc(
    const float* __restrict__ Whh_f, const float* __restrict__ Whh_b,
    const float* __restrict__ out_W,
    unsigned short* __restrict__ Whh_bf, unsigned short* __restrict__ outW_bf)
{
    int idx = blockIdx.x * 256 + threadIdx.x;
    int stride = gridDim.x * 256;
    for (int i = idx; i < 1024 * HHX; i += stride) {
        int G = i >> 7, k = i & 127;
        int dir = G >> 9, gp = G & 511;
        int orig = orig_of(gp);
        const float* Whh = dir ? Whh_b : Whh_f;
        Whh_bf[i] = f2bf(Whh[orig * HHX + k]);
    }
    for (int i = idx; i < LBL * 256; i += stride) outW_bf[i] = f2bf(out_W[i]);
}

// ---------------- big GEMM: P2 = S @ Wc^T + bc, written in LSTM-thread layout ----------------
// P2[t][dir][bt][tid(512)][16]: each LSTM thread's 16 gate pre-acts contiguous (32B).
__global__ __launch_bounds__(512) void k_gemm_p(
    const float* __restrict__ S, const unsigned short* __restrict__ Wc,
    const float* __restrict__ bc, unsigned short* __restrict__ P2)
{
    int m0 = blockIdx.y * 64;
    int n0 = blockIdx.x * 256;
    int tid = threadIdx.x;
    int w = tid >> 6, l = tid & 63;
    int lr = l & 15, lq = l >> 4;
    int wm = w >> 2, wn = w & 3;

    __shared__ __align__(16) unsigned short Alds[64 * 64];
    __shared__ __align__(16) unsigned short Blds[256 * 64];

    const f32x4 fzero = {0.f, 0.f, 0.f, 0.f};
    f32x4 acc[2][4];
    #pragma unroll
    for (int a = 0; a < 2; ++a)
        #pragma unroll
        for (int b = 0; b < 4; ++b) acc[a][b] = fzero;

    for (int kt = 0; kt < 8; ++kt) {
        { // stage A (convert fp32->bf16, XOR-swizzled rows of 128B)
            int r = tid >> 3, c = tid & 7;
            const float* src = S + (size_t)(m0 + r) * INDIM + kt * 64 + c * 8;
            float4 v0 = *(const float4*)src;
            float4 v1 = *(const float4*)(src + 4);
            bf16x8 wv;
            wv[0] = (short)f2bf(v0.x); wv[1] = (short)f2bf(v0.y);
            wv[2] = (short)f2bf(v0.z); wv[3] = (short)f2bf(v0.w);
            wv[4] = (short)f2bf(v1.x); wv[5] = (short)f2bf(v1.y);
            wv[6] = (short)f2bf(v1.z); wv[7] = (short)f2bf(v1.w);
            *(bf16x8*)((char*)Alds + r * 128 + ((c * 16) ^ ((r & 7) << 4))) = wv;
        }
        { // stage B
            int r = tid >> 1, h = tid & 1;
            const unsigned short* bs = Wc + (size_t)(n0 + r) * INDIM + kt * 64;
            #pragma unroll
            for (int cc = 0; cc < 4; ++cc) {
                int ch = h * 4 + cc;
                bf16x8 v = *(const bf16x8*)(bs + ch * 8);
                *(bf16x8*)((char*)Blds + r * 128 + ((ch * 16) ^ ((r & 7) << 4))) = v;
            }
        }
        __syncthreads();
        bf16x8 af[2][2], bfv[4][2];
        #pragma unroll
        for (int tm = 0; tm < 2; ++tm)
            #pragma unroll
            for (int kk = 0; kk < 2; ++kk) {
                int ra = wm * 32 + tm * 16 + lr;
                af[tm][kk] = *(const bf16x8*)((char*)Alds + ra * 128 + ((kk * 64 + lq * 16) ^ ((ra & 7) << 4)));
            }
        #pragma unroll
        for (int tn = 0; tn < 4; ++tn)
            #pragma unroll
            for (int kk = 0; kk < 2; ++kk) {
                int rb = wn * 64 + tn * 16 + lr;
                bfv[tn][kk] = *(const bf16x8*)((char*)Blds + rb * 128 + ((kk * 64 + lq * 16) ^ ((rb & 7) << 4)));
            }
        #pragma unroll
        for (int tm = 0; tm < 2; ++tm)
            #pragma unroll
            for (int tn = 0; tn < 4; ++tn)
                #pragma unroll
                for (int kk = 0; kk < 2; ++kk)
                    acc[tm][tn] = __builtin_amdgcn_mfma_f32_16x16x32_bf16(af[tm][kk], bfv[tn][kk], acc[tm][tn], 0, 0, 0);
        __syncthreads();
    }
    // epilogue: scatter into LSTM-thread layout
    #pragma unroll
    for (int tn = 0; tn < 4; ++tn) {
        int n = n0 + wn * 64 + tn * 16 + lr;
        float bias = bc[n];
        int dir2 = n >> 9, nn = n & 511;
        int w2 = nn >> 6, q2 = (nn >> 4) & 3, lr2 = nn & 15;
        #pragma unroll
        for (int tm = 0; tm < 2; ++tm) {
            #pragma unroll
            for (int j = 0; j < 4; ++j) {
                int m = m0 + wm * 32 + tm * 16 + lq * 4 + j;
                int t = m >> 5, mb = m & 31;
                int bt2 = mb >> 4, lq2 = (mb >> 2) & 3, j2 = mb & 3;
                size_t idx = ((size_t)(t * 4 + dir2 * 2 + bt2) * 512 + (w2 * 64 + lq2 * 16 + lr2)) * 16
                             + q2 * 4 + j2;
                P2[idx] = f2bf(acc[tm][tn][j] + bias);
            }
        }
    }
}

// ---------------- LSTM recurrence: 4 blocks (dir x batch-tile), 512 threads ----------------
__global__ __launch_bounds__(512) void k_lstm(
    const unsigned short* __restrict__ P2, const unsigned short* __restrict__ Whh_bf,
    const float* __restrict__ h0, const float* __restrict__ c0,
    unsigned short* __restrict__ H)
{
    int blk = blockIdx.x;
    int dir = blk >> 1, bt = blk & 1;
    int tid = threadIdx.x;
    int w = tid >> 6, l = tid & 63;
    int lr = l & 15, lq = l >> 4;

    __shared__ __align__(16) unsigned short hbuf[2][16 * 128];

    // Whh fragments: wave w owns gates q=0..3 of units [w*16, w*16+16)
    bf16x8 bfrag[4][4];
    #pragma unroll
    for (int q = 0; q < 4; ++q)
        #pragma unroll
        for (int ko = 0; ko < 4; ++ko) {
            int row = dir * 512 + w * 64 + q * 16 + lr;
            bfrag[q][ko] = *(const bf16x8*)(Whh_bf + (size_t)row * HHX + ko * 32 + lq * 8);
        }

    float c_reg[4];
    #pragma unroll
    for (int j = 0; j < 4; ++j)
        c_reg[j] = c0[(dir * 32 + bt * 16 + lq * 4 + j) * HHX + w * 16 + lr];

    for (int e = tid; e < 2048; e += 512) {
        int b = e >> 7, u = e & 127;
        float hv = h0[(dir * 32 + bt * 16 + b) * HHX + u];
        *(unsigned short*)((char*)hbuf[0] + ((b * 256 + u * 2) ^ ((b & 7) << 4))) = f2bf(hv);
    }
    __syncthreads();

    int t0 = dir ? (SEQT - 1) : 0;
    const long long pstep = (dir ? -1LL : 1LL) * (4 * 512 * 16);  // elements per t-step
    const unsigned short* pptr = P2 + ((size_t)(t0 * 4 + dir * 2 + bt) * 512 + tid) * 16;
    bf16x8 pc0 = *(const bf16x8*)pptr;
    bf16x8 pc1 = *(const bf16x8*)(pptr + 8);
    pptr += pstep;

    // H store base: H[(t*32 + bt*16 + lq*4 + j)*256 + dir*128 + w*16 + lr]
    unsigned short* hbase = H + (size_t)(bt * 16 + lq * 4) * 256 + dir * 128 + w * 16 + lr
                              + (size_t)t0 * 32 * 256;
    const long long hstep = (dir ? -1LL : 1LL) * (32 * 256);

    int cur = 0;
    for (int tt = 0; tt < SEQT; ++tt) {
        bf16x8 pn0 = pc0, pn1 = pc1;
        if (tt + 1 < SEQT) {
            pn0 = *(const bf16x8*)pptr;
            pn1 = *(const bf16x8*)(pptr + 8);
            pptr += pstep;
        }
        bf16x8 af[4];
        #pragma unroll
        for (int ko = 0; ko < 4; ++ko)
            af[ko] = *(const bf16x8*)((char*)hbuf[cur] + ((lr * 256 + ko * 64 + lq * 16) ^ ((lr & 7) << 4)));
        f32x4 acc[4];
        #pragma unroll
        for (int q = 0; q < 4; ++q) {
            f32x4 a = {0.f, 0.f, 0.f, 0.f};
            #pragma unroll
            for (int ko = 0; ko < 4; ++ko)
                a = __builtin_amdgcn_mfma_f32_16x16x32_bf16(af[ko], bfrag[q][ko], a, 0, 0, 0);
            acc[q] = a;
        }
        float hn[4];
        #pragma unroll
        for (int j = 0; j < 4; ++j) {
            float ig = acc[0][j] + bf2f((unsigned short)pc0[0 + j]);
            float fg = acc[1][j] + bf2f((unsigned short)pc0[4 + j]);
            float gg = acc[2][j] + bf2f((unsigned short)pc1[0 + j]);
            float og = acc[3][j] + bf2f((unsigned short)pc1[4 + j]);
            float cn = sigm(fg) * c_reg[j] + sigm(ig) * tanh_(gg);
            c_reg[j] = cn;
            hn[j] = sigm(og) * tanh_(cn);
        }
        #pragma unroll
        for (int j = 0; j < 4; ++j) {
            int b = lq * 4 + j, u = w * 16 + lr;
            unsigned short hb = f2bf(hn[j]);
            *(unsigned short*)((char*)hbuf[cur ^ 1] + ((b * 256 + u * 2) ^ ((b & 7) << 4))) = hb;
            hbase[j * 256] = hb;
        }
        hbase += hstep;
        pc0 = pn0; pc1 = pn1;
        cur ^= 1;
        __syncthreads();
    }
}

// ---------------- feats: F(65536x16) = H @ outW^T + out_b ----------------
__global__ __launch_bounds__(256) void k_feats(
    const unsigned short* __restrict__ H, const unsigned short* __restrict__ outW_bf,
    const float* __restrict__ out_b, float* __restrict__ feats)
{
    int m0 = blockIdx.x * 64;
    int tid = threadIdx.x;
    int w = tid >> 6, l = tid & 63;
    int lr = l & 15, lq = l >> 4;
    __shared__ __align__(16) unsigned short Hl[64 * 256];

    {
        int r = tid >> 2, cb = (tid & 3) * 8;
        #pragma unroll
        for (int cc = 0; cc < 8; ++cc) {
            int c = cb + cc;
            bf16x8 v = *(const bf16x8*)(H + (size_t)(m0 + r) * 256 + c * 8);
            *(bf16x8*)((char*)Hl + r * 512 + ((c * 16) ^ ((r & 7) << 4))) = v;
        }
    }
    bf16x8 bw[8];
    #pragma unroll
    for (int ko = 0; ko < 8; ++ko)
        bw[ko] = *(const bf16x8*)(outW_bf + lr * 256 + ko * 32 + lq * 8);
    __syncthreads();
    int row = w * 16 + lr;
    f32x4 acc = {0.f, 0.f, 0.f, 0.f};
    #pragma unroll
    for (int ko = 0; ko < 8; ++ko) {
        bf16x8 a = *(const bf16x8*)((char*)Hl + row * 512 + ((ko * 64 + lq * 16) ^ ((row & 7) << 4)));
        acc = __builtin_amdgcn_mfma_f32_16x16x32_bf16(a, bw[ko], acc, 0, 0, 0);
    }
    float ob = out_b[lr];
    #pragma unroll
    for (int j = 0; j < 4; ++j) {
        int m = m0 + w * 16 + lq * 4 + j;
        feats[(size_t)m * 16 + lr] = acc[j] + ob;
    }
}

// ---------------- Viterbi: 1 block per batch, 1 wave ----------------
__global__ __launch_bounds__(64) void k_viterbi(
    const float* __restrict__ feats, const float* __restrict__ trans,
    float* __restrict__ out)
{
    int b = blockIdx.x;
    int l = threadIdx.x;
    int i = l >> 2, s = l & 3;          // i = next-label (0..15), s = prev-quad (0..3)
    __shared__ unsigned char bp[SEQT * 16];
    __shared__ __align__(16) float fch[256 * 16];

    float tr[4];
    #pragma unroll
    for (int m = 0; m < 4; ++m) tr[m] = trans[i * 16 + s * 4 + m];
    // lane holds fv[s*4+m], m=0..3
    float fvloc[4];
    #pragma unroll
    for (int m = 0; m < 4; ++m) fvloc[m] = (s * 4 + m == 0) ? 0.f : -10000.f;

    for (int t = 0; t < SEQT; ++t) {
        if ((t & 255) == 0) {
            __syncthreads();
            for (int k = l; k < 256; k += 64) {
                const float4* src = (const float4*)(feats + (size_t)((t + k) * 32 + b) * 16);
                float4 v0 = src[0], v1 = src[1], v2 = src[2], v3 = src[3];
                float4* dst = (float4*)(fch + k * 16);
                dst[0] = v0; dst[1] = v1; dst[2] = v2; dst[3] = v3;
            }
            __syncthreads();
        }
        float best = fvloc[0] + tr[0];
        int bj = s * 4;
        #pragma unroll
        for (int m = 1; m < 4; ++m) {
            float v = fvloc[m] + tr[m];
            if (v > best) { best = v; bj = s * 4 + m; }
        }
        #pragma unroll
        for (int off = 1; off <= 2; off <<= 1) {
            float ov = __shfl_xor(best, off);
            int oj = __shfl_xor(bj, off);
            if (ov > best || (ov == best && oj < bj)) { best = ov; bj = oj; }
        }
        float fvn = best + fch[(t & 255) * 16 + i];
        if (s == 0) bp[t * 16 + i] = (unsigned char)bj;
        #pragma unroll
        for (int m = 0; m < 4; ++m) fvloc[m] = __shfl(fvn, 16 * s + 4 * m);
    }
    // termination: lane (i,s) holds fv[4s..4s+3]; reduce over all 16 via xor 1,2
    float bestS = fvloc[0] + trans[16 + s * 4];
    int bl = s * 4;
    #pragma unroll
    for (int m = 1; m < 4; ++m) {
        float tv = fvloc[m] + trans[16 + s * 4 + m];
        if (tv > bestS) { bestS = tv; bl = s * 4 + m; }
    }
    #pragma unroll
    for (int off = 1; off <= 2; off <<= 1) {
        float ov = __shfl_xor(bestS, off);
        int oj = __shfl_xor(bl, off);
        if (ov > bestS || (ov == bestS && oj < bl)) { bestS = ov; bl = oj; }
    }
    __syncthreads();
    if (l == 0) {
        out[b] = bestS;
        int lbl = bl;
        for (int t = SEQT - 1; t >= 0; --t) {
            out[32 + (size_t)t * 32 + b] = (float)lbl;
            lbl = bp[t * 16 + lbl];
        }
    }
}

extern "C" void kernel_launch(void* const* d_in, const int* in_sizes, int n_in,
                              void* d_out, int out_size, void* d_ws, size_t ws_size,
                              hipStream_t stream) {
    const float* source = (const float*)d_in[0];
    const float* in_W  = (const float*)d_in[1];
    const float* in_b  = (const float*)d_in[2];
    const float* Wih_f = (const float*)d_in[3];
    const float* Whh_f = (const float*)d_in[4];
    const float* b_f   = (const float*)d_in[5];
    const float* Wih_b = (const float*)d_in[6];
    const float* Whh_b = (const float*)d_in[7];
    const float* b_b   = (const float*)d_in[8];
    const float* out_W = (const float*)d_in[9];
    const float* out_b = (const float*)d_in[10];
    const float* trans = (const float*)d_in[11];
    const float* h0    = (const float*)d_in[12];
    const float* c0    = (const float*)d_in[13];
    float* out = (float*)d_out;

    char* ws = (char*)d_ws;
    unsigned short* P2      = (unsigned short*)(ws);                 // 65536*1024*2 = 134217728
    unsigned short* H       = (unsigned short*)(ws + 134217728);     // 65536*256*2  =  33554432
    float*          feats   = (float*)         (ws + 167772160);     // 65536*16*4   =   4194304
    unsigned short* Wc      = (unsigned short*)(ws + 171966464);     // 1024*512*2   =   1048576
    float*          bc      = (float*)         (ws + 173015040);     // 1024*4
    unsigned short* Whh_bf  = (unsigned short*)(ws + 173019136);     // 1024*128*2   =    262144
    unsigned short* outW_bf = (unsigned short*)(ws + 173281280);     // 16*256*2
    // total ~173.3 MB

    hipLaunchKernelGGL(k_prep_wc, dim3(1024), dim3(256), 0, stream,
                       in_W, in_b, Wih_f, b_f, Wih_b, b_b, Wc, bc);
    hipLaunchKernelGGL(k_prep_misc, dim3(256), dim3(256), 0, stream,
                       Whh_f, Whh_b, out_W, Whh_bf, outW_bf);
    hipLaunchKernelGGL(k_gemm_p, dim3(4, 1024), dim3(512), 0, stream,
                       source, Wc, bc, P2);
    hipLaunchKernelGGL(k_lstm, dim3(4), dim3(512), 0, stream,
                       P2, Whh_bf, h0, c0, H);
    hipLaunchKernelGGL(k_feats, dim3(1024), dim3(256), 0, stream,
                       H, outW_bf, out_b, feats);
    hipLaunchKernelGGL(k_viterbi, dim3(32), dim3(64), 0, stream,
                       feats, trans, out);
}

// Round 3
// 2596.584 us; speedup vs baseline: 2.1492x; 1.0903x over previous
//
#include <hip/hip_runtime.h>
#include <hip/hip_bf16.h>

typedef __attribute__((ext_vector_type(8))) short bf16x8;
typedef __attribute__((ext_vector_type(4))) float f32x4;
typedef __attribute__((ext_vector_type(4))) unsigned u32x4;
typedef __attribute__((ext_vector_type(2))) unsigned u32x2;

#define SEQT 2048
#define BATCH 32
#define INDIM 512
#define EMB 256
#define HHX 128
#define LBL 16
#define LOG2E 1.44269504f

__device__ __forceinline__ unsigned short f2bf(float f) {
    unsigned u = __float_as_uint(f);
    u += 0x7FFFu + ((u >> 16) & 1u);
    return (unsigned short)(u >> 16);
}
#define BLO(u) __uint_as_float((u) << 16)
#define BHI(u) __uint_as_float((u) & 0xffff0000u)

// merged-rcp LSTM cell: 5 exp2 + 3 rcp. Saturation-safe:
//  - positive-arg exp2s clamped at 80 (finite), all other inf paths give exact 0 limits.
__device__ __forceinline__ float cell(float ig, float fg, float gg, float og, float& c) {
    float Ef = __builtin_amdgcn_exp2f(-LOG2E * fg);
    float Ei = __builtin_amdgcn_exp2f(-LOG2E * ig);
    float Eg = __builtin_amdgcn_exp2f(fminf(2.f * LOG2E * gg, 80.f));
    float Eo = __builtin_amdgcn_exp2f(-LOG2E * og);
    float r1 = __builtin_amdgcn_rcpf(1.f + Ef);
    float r2 = __builtin_amdgcn_rcpf((Eg + 1.f) * (1.f + Ei));
    float cn = c * r1 + (Eg - 1.f) * r2;
    c = cn;
    float E2 = __builtin_amdgcn_exp2f(fminf(2.f * LOG2E * cn, 80.f));
    float r3 = __builtin_amdgcn_rcpf((E2 + 1.f) * (1.f + Eo));
    return (E2 - 1.f) * r3;
}

// Gate-row permutation: g' = w*64 + q*16 + r  <->  orig = q*128 + w*16 + r
__device__ __forceinline__ int orig_of(int gp) {
    return ((gp >> 4) & 3) * 128 + (gp >> 6) * 16 + (gp & 15);
}

// ---------------- prep: combined W (Wih @ in_W) + bias, permuted rows; 8 rows/block ----------------
__global__ __launch_bounds__(256) void k_prep_wc(
    const float* __restrict__ in_W, const float* __restrict__ in_b,
    const float* __restrict__ Wih_f, const float* __restrict__ b_f,
    const float* __restrict__ Wih_b, const float* __restrict__ b_b,
    unsigned short* __restrict__ Wc, float* __restrict__ bc)
{
    int G0 = blockIdx.x * 8;         // 128 blocks
    int tid = threadIdx.x;
    __shared__ float wrow[8][EMB];
    for (int e = tid; e < 8 * EMB; e += 256) {
        int r = e >> 8, ee = e & 255;
        int G = G0 + r, dir = G >> 9;
        wrow[r][ee] = (dir ? Wih_b : Wih_f)[orig_of(G & 511) * EMB + ee];
    }
    __syncthreads();
    for (int k = tid; k < INDIM; k += 256) {
        float acc[8] = {0, 0, 0, 0, 0, 0, 0, 0};
        #pragma unroll 4
        for (int e = 0; e < EMB; ++e) {
            float x = in_W[e * INDIM + k];
            #pragma unroll
            for (int r = 0; r < 8; ++r) acc[r] += wrow[r][e] * x;
        }
        #pragma unroll
        for (int r = 0; r < 8; ++r) Wc[(size_t)(G0 + r) * INDIM + k] = f2bf(acc[r]);
    }
    if (tid < 64) {
        for (int r = 0; r < 8; ++r) {
            float p = 0.f;
            for (int e = tid; e < EMB; e += 64) p += wrow[r][e] * in_b[e];
            for (int off = 32; off; off >>= 1) p += __shfl_xor(p, off);
            if (tid == 0) {
                int G = G0 + r, dir = G >> 9;
                bc[G] = (dir ? b_b : b_f)[orig_of(G & 511)] + p;
            }
        }
    }
}

// ---------------- prep: bf16 converts (Whh permuted, out_W) ----------------
__global__ __launch_bounds__(256) void k_prep_misc(
    const float* __restrict__ Whh_f, const float* __restrict__ Whh_b,
    const float* __restrict__ out_W,
    unsigned short* __restrict__ Whh_bf, unsigned short* __restrict__ outW_bf)
{
    int idx = blockIdx.x * 256 + threadIdx.x;
    int stride = gridDim.x * 256;
    for (int i = idx; i < 1024 * HHX; i += stride) {
        int G = i >> 7, k = i & 127;
        int dir = G >> 9;
        const float* Whh = dir ? Whh_b : Whh_f;
        Whh_bf[i] = f2bf(Whh[orig_of(G & 511) * HHX + k]);
    }
    for (int i = idx; i < LBL * 256; i += stride) outW_bf[i] = f2bf(out_W[i]);
}

// ---------------- big GEMM: P2 = S @ Wc^T + bc, written in LSTM-thread layout ----------------
// P2[t][dir][bt][tid(512)][16]: each LSTM thread's 16 gate pre-acts contiguous (32B).
__global__ __launch_bounds__(512) void k_gemm_p(
    const float* __restrict__ S, const unsigned short* __restrict__ Wc,
    const float* __restrict__ bc, unsigned short* __restrict__ P2)
{
    int m0 = blockIdx.y * 64;
    int n0 = blockIdx.x * 256;
    int tid = threadIdx.x;
    int w = tid >> 6, l = tid & 63;
    int lr = l & 15, lq = l >> 4;
    int wm = w >> 2, wn = w & 3;

    __shared__ __align__(16) unsigned short Alds[64 * 64];
    __shared__ __align__(16) unsigned short Blds[256 * 64];

    const f32x4 fzero = {0.f, 0.f, 0.f, 0.f};
    f32x4 acc[2][4];
    #pragma unroll
    for (int a = 0; a < 2; ++a)
        #pragma unroll
        for (int b = 0; b < 4; ++b) acc[a][b] = fzero;

    for (int kt = 0; kt < 8; ++kt) {
        { // stage A (convert fp32->bf16 via cvt_pk, XOR-swizzled rows of 128B)
            int r = tid >> 3, c = tid & 7;
            const float* src = S + (size_t)(m0 + r) * INDIM + kt * 64 + c * 8;
            float4 v0 = *(const float4*)src;
            float4 v1 = *(const float4*)(src + 4);
            unsigned g0, g1, g2, g3;
            asm("v_cvt_pk_bf16_f32 %0, %1, %2" : "=v"(g0) : "v"(v0.x), "v"(v0.y));
            asm("v_cvt_pk_bf16_f32 %0, %1, %2" : "=v"(g1) : "v"(v0.z), "v"(v0.w));
            asm("v_cvt_pk_bf16_f32 %0, %1, %2" : "=v"(g2) : "v"(v1.x), "v"(v1.y));
            asm("v_cvt_pk_bf16_f32 %0, %1, %2" : "=v"(g3) : "v"(v1.z), "v"(v1.w));
            u32x4 wv = {g0, g1, g2, g3};
            *(u32x4*)((char*)Alds + r * 128 + ((c * 16) ^ ((r & 7) << 4))) = wv;
        }
        { // stage B
            int r = tid >> 1, h = tid & 1;
            const unsigned short* bs = Wc + (size_t)(n0 + r) * INDIM + kt * 64;
            #pragma unroll
            for (int cc = 0; cc < 4; ++cc) {
                int ch = h * 4 + cc;
                bf16x8 v = *(const bf16x8*)(bs + ch * 8);
                *(bf16x8*)((char*)Blds + r * 128 + ((ch * 16) ^ ((r & 7) << 4))) = v;
            }
        }
        __syncthreads();
        bf16x8 af[2][2], bfv[4][2];
        #pragma unroll
        for (int tm = 0; tm < 2; ++tm)
            #pragma unroll
            for (int kk = 0; kk < 2; ++kk) {
                int ra = wm * 32 + tm * 16 + lr;
                af[tm][kk] = *(const bf16x8*)((char*)Alds + ra * 128 + ((kk * 64 + lq * 16) ^ ((ra & 7) << 4)));
            }
        #pragma unroll
        for (int tn = 0; tn < 4; ++tn)
            #pragma unroll
            for (int kk = 0; kk < 2; ++kk) {
                int rb = wn * 64 + tn * 16 + lr;
                bfv[tn][kk] = *(const bf16x8*)((char*)Blds + rb * 128 + ((kk * 64 + lq * 16) ^ ((rb & 7) << 4)));
            }
        #pragma unroll
        for (int tm = 0; tm < 2; ++tm)
            #pragma unroll
            for (int tn = 0; tn < 4; ++tn)
                #pragma unroll
                for (int kk = 0; kk < 2; ++kk)
                    acc[tm][tn] = __builtin_amdgcn_mfma_f32_16x16x32_bf16(af[tm][kk], bfv[tn][kk], acc[tm][tn], 0, 0, 0);
        __syncthreads();
    }
    // epilogue: packed dwordx2 stores into LSTM-thread layout
    #pragma unroll
    for (int tn = 0; tn < 4; ++tn) {
        int n = n0 + wn * 64 + tn * 16 + lr;
        float bias = bc[n];
        int dir2 = n >> 9, nn = n & 511;
        int w2 = nn >> 6, q2 = (nn >> 4) & 3, lr2 = nn & 15;
        #pragma unroll
        for (int tm = 0; tm < 2; ++tm) {
            int t = blockIdx.y * 2 + wm;
            size_t base = ((size_t)(t * 4 + dir2 * 2 + tm) * 512 + (w2 * 64 + lq * 16 + lr2)) * 16 + q2 * 4;
            float f0 = acc[tm][tn][0] + bias, f1 = acc[tm][tn][1] + bias;
            float f2 = acc[tm][tn][2] + bias, f3 = acc[tm][tn][3] + bias;
            unsigned p01, p23;
            asm("v_cvt_pk_bf16_f32 %0, %1, %2" : "=v"(p01) : "v"(f0), "v"(f1));
            asm("v_cvt_pk_bf16_f32 %0, %1, %2" : "=v"(p23) : "v"(f2), "v"(f3));
            *(u32x2*)(P2 + base) = (u32x2){p01, p23};
        }
    }
}

// ---------------- LSTM recurrence: 4 blocks (dir x batch-tile), 512 threads ----------------
__global__ __launch_bounds__(512) void k_lstm(
    const unsigned short* __restrict__ P2, const unsigned short* __restrict__ Whh_bf,
    const float* __restrict__ h0, const float* __restrict__ c0,
    unsigned short* __restrict__ H)
{
    int blk = blockIdx.x;
    int dir = blk >> 1, bt = blk & 1;
    int tid = threadIdx.x;
    int w = tid >> 6, l = tid & 63;
    int lr = l & 15, lq = l >> 4;

    __shared__ __align__(16) unsigned short hbuf[2][16 * 128];
    char* hb = (char*)hbuf;

    // Whh fragments: wave w owns gates q=0..3 of units [w*16, w*16+16)
    bf16x8 bfrag[4][4];
    #pragma unroll
    for (int q = 0; q < 4; ++q)
        #pragma unroll
        for (int ko = 0; ko < 4; ++ko) {
            int row = dir * 512 + w * 64 + q * 16 + lr;
            bfrag[q][ko] = *(const bf16x8*)(Whh_bf + (size_t)row * HHX + ko * 32 + lq * 8);
        }

    float c_reg[4];
    #pragma unroll
    for (int j = 0; j < 4; ++j)
        c_reg[j] = c0[(dir * 32 + bt * 16 + lq * 4 + j) * HHX + w * 16 + lr];

    for (int e = tid; e < 2048; e += 512) {
        int b = e >> 7, u = e & 127;
        float hv = h0[(dir * 32 + bt * 16 + b) * HHX + u];
        *(unsigned short*)(hb + ((b * 256 + u * 2) ^ ((b & 7) << 4))) = f2bf(hv);
    }
    __syncthreads();

    // loop-invariant LDS offsets
    const int rd0 = (lr * 256 + 0 * 64 + lq * 16) ^ ((lr & 7) << 4);
    const int rd1 = (lr * 256 + 1 * 64 + lq * 16) ^ ((lr & 7) << 4);
    const int rd2 = (lr * 256 + 2 * 64 + lq * 16) ^ ((lr & 7) << 4);
    const int rd3 = (lr * 256 + 3 * 64 + lq * 16) ^ ((lr & 7) << 4);
    const int ub = (w * 16 + lr) * 2;
    const int w0 = ((lq * 4 + 0) * 256 + ub) ^ (((lq * 4 + 0) & 7) << 4);
    const int w1 = ((lq * 4 + 1) * 256 + ub) ^ (((lq * 4 + 1) & 7) << 4);
    const int w2 = ((lq * 4 + 2) * 256 + ub) ^ (((lq * 4 + 2) & 7) << 4);
    const int w3 = ((lq * 4 + 3) * 256 + ub) ^ (((lq * 4 + 3) & 7) << 4);

    int t0 = dir ? (SEQT - 1) : 0;
    const long long pstep = (dir ? -1LL : 1LL) * (4 * 512 * 16);
    const unsigned short* pptr = P2 + ((size_t)(t0 * 4 + dir * 2 + bt) * 512 + tid) * 16;
    bf16x8 pc0 = *(const bf16x8*)pptr;
    bf16x8 pc1 = *(const bf16x8*)(pptr + 8);
    pptr += pstep;

    unsigned short* hbase = H + (size_t)(bt * 16 + lq * 4) * 256 + dir * 128 + w * 16 + lr
                              + (size_t)t0 * 32 * 256;
    const long long hstep = (dir ? -1LL : 1LL) * (32 * 256);

#define STEP(CUR, PF) do { \
    bf16x8 af0 = *(const bf16x8*)(hb + (CUR) * 4096 + rd0); \
    bf16x8 af1 = *(const bf16x8*)(hb + (CUR) * 4096 + rd1); \
    bf16x8 af2 = *(const bf16x8*)(hb + (CUR) * 4096 + rd2); \
    bf16x8 af3 = *(const bf16x8*)(hb + (CUR) * 4096 + rd3); \
    u32x4 u0 = __builtin_bit_cast(u32x4, pc0); \
    u32x4 u1 = __builtin_bit_cast(u32x4, pc1); \
    if (PF) { pc0 = *(const bf16x8*)pptr; pc1 = *(const bf16x8*)(pptr + 8); pptr += pstep; } \
    f32x4 a0 = {BLO(u0.x), BHI(u0.x), BLO(u0.y), BHI(u0.y)}; \
    f32x4 a1 = {BLO(u0.z), BHI(u0.z), BLO(u0.w), BHI(u0.w)}; \
    f32x4 a2 = {BLO(u1.x), BHI(u1.x), BLO(u1.y), BHI(u1.y)}; \
    f32x4 a3 = {BLO(u1.z), BHI(u1.z), BLO(u1.w), BHI(u1.w)}; \
    a0 = __builtin_amdgcn_mfma_f32_16x16x32_bf16(af0, bfrag[0][0], a0, 0, 0, 0); \
    a0 = __builtin_amdgcn_mfma_f32_16x16x32_bf16(af1, bfrag[0][1], a0, 0, 0, 0); \
    a0 = __builtin_amdgcn_mfma_f32_16x16x32_bf16(af2, bfrag[0][2], a0, 0, 0, 0); \
    a0 = __builtin_amdgcn_mfma_f32_16x16x32_bf16(af3, bfrag[0][3], a0, 0, 0, 0); \
    a1 = __builtin_amdgcn_mfma_f32_16x16x32_bf16(af0, bfrag[1][0], a1, 0, 0, 0); \
    a1 = __builtin_amdgcn_mfma_f32_16x16x32_bf16(af1, bfrag[1][1], a1, 0, 0, 0); \
    a1 = __builtin_amdgcn_mfma_f32_16x16x32_bf16(af2, bfrag[1][2], a1, 0, 0, 0); \
    a1 = __builtin_amdgcn_mfma_f32_16x16x32_bf16(af3, bfrag[1][3], a1, 0, 0, 0); \
    a2 = __builtin_amdgcn_mfma_f32_16x16x32_bf16(af0, bfrag[2][0], a2, 0, 0, 0); \
    a2 = __builtin_amdgcn_mfma_f32_16x16x32_bf16(af1, bfrag[2][1], a2, 0, 0, 0); \
    a2 = __builtin_amdgcn_mfma_f32_16x16x32_bf16(af2, bfrag[2][2], a2, 0, 0, 0); \
    a2 = __builtin_amdgcn_mfma_f32_16x16x32_bf16(af3, bfrag[2][3], a2, 0, 0, 0); \
    a3 = __builtin_amdgcn_mfma_f32_16x16x32_bf16(af0, bfrag[3][0], a3, 0, 0, 0); \
    a3 = __builtin_amdgcn_mfma_f32_16x16x32_bf16(af1, bfrag[3][1], a3, 0, 0, 0); \
    a3 = __builtin_amdgcn_mfma_f32_16x16x32_bf16(af2, bfrag[3][2], a3, 0, 0, 0); \
    a3 = __builtin_amdgcn_mfma_f32_16x16x32_bf16(af3, bfrag[3][3], a3, 0, 0, 0); \
    float hn0 = cell(a0[0], a1[0], a2[0], a3[0], c_reg[0]); \
    float hn1 = cell(a0[1], a1[1], a2[1], a3[1], c_reg[1]); \
    float hn2 = cell(a0[2], a1[2], a2[2], a3[2], c_reg[2]); \
    float hn3 = cell(a0[3], a1[3], a2[3], a3[3], c_reg[3]); \
    unsigned pk01, pk23; \
    asm("v_cvt_pk_bf16_f32 %0, %1, %2" : "=v"(pk01) : "v"(hn0), "v"(hn1)); \
    asm("v_cvt_pk_bf16_f32 %0, %1, %2" : "=v"(pk23) : "v"(hn2), "v"(hn3)); \
    unsigned short s0 = (unsigned short)pk01, s1 = (unsigned short)(pk01 >> 16); \
    unsigned short s2 = (unsigned short)pk23, s3 = (unsigned short)(pk23 >> 16); \
    char* wb = hb + (((CUR) ^ 1) * 4096); \
    *(unsigned short*)(wb + w0) = s0; \
    *(unsigned short*)(wb + w1) = s1; \
    *(unsigned short*)(wb + w2) = s2; \
    *(unsigned short*)(wb + w3) = s3; \
    hbase[0] = s0; hbase[256] = s1; hbase[512] = s2; hbase[768] = s3; \
    hbase += hstep; \
    __syncthreads(); \
} while (0)

    for (int it = 0; it < 1023; ++it) {
        STEP(0, true);
        STEP(1, true);
    }
    STEP(0, true);
    STEP(1, false);
#undef STEP
}

// ---------------- feats: F(65536x16) = H @ outW^T + out_b ----------------
__global__ __launch_bounds__(256) void k_feats(
    const unsigned short* __restrict__ H, const unsigned short* __restrict__ outW_bf,
    const float* __restrict__ out_b, float* __restrict__ feats)
{
    int m0 = blockIdx.x * 64;
    int tid = threadIdx.x;
    int w = tid >> 6, l = tid & 63;
    int lr = l & 15, lq = l >> 4;
    __shared__ __align__(16) unsigned short Hl[64 * 256];

    {
        int r = tid >> 2, cb = (tid & 3) * 8;
        #pragma unroll
        for (int cc = 0; cc < 8; ++cc) {
            int c = cb + cc;
            bf16x8 v = *(const bf16x8*)(H + (size_t)(m0 + r) * 256 + c * 8);
            *(bf16x8*)((char*)Hl + r * 512 + ((c * 16) ^ ((r & 7) << 4))) = v;
        }
    }
    bf16x8 bw[8];
    #pragma unroll
    for (int ko = 0; ko < 8; ++ko)
        bw[ko] = *(const bf16x8*)(outW_bf + lr * 256 + ko * 32 + lq * 8);
    __syncthreads();
    int row = w * 16 + lr;
    f32x4 acc = {0.f, 0.f, 0.f, 0.f};
    #pragma unroll
    for (int ko = 0; ko < 8; ++ko) {
        bf16x8 a = *(const bf16x8*)((char*)Hl + row * 512 + ((ko * 64 + lq * 16) ^ ((row & 7) << 4)));
        acc = __builtin_amdgcn_mfma_f32_16x16x32_bf16(a, bw[ko], acc, 0, 0, 0);
    }
    float ob = out_b[lr];
    #pragma unroll
    for (int j = 0; j < 4; ++j) {
        int m = m0 + w * 16 + lq * 4 + j;
        feats[(size_t)m * 16 + lr] = acc[j] + ob;
    }
}

// ---------------- Viterbi: 1 block per batch, 1 wave ----------------
__global__ __launch_bounds__(64) void k_viterbi(
    const float* __restrict__ feats, const float* __restrict__ trans,
    float* __restrict__ out)
{
    int b = blockIdx.x;
    int l = threadIdx.x;
    int i = l >> 2, s = l & 3;          // i = next-label (0..15), s = prev-quad (0..3)
    __shared__ unsigned char bp[SEQT * 16];
    __shared__ __align__(16) float fch[256 * 16];
    __shared__ unsigned char path[SEQT];

    float tr[4];
    #pragma unroll
    for (int m = 0; m < 4; ++m) tr[m] = trans[i * 16 + s * 4 + m];
    float fvloc[4];
    #pragma unroll
    for (int m = 0; m < 4; ++m) fvloc[m] = (s * 4 + m == 0) ? 0.f : -10000.f;

    for (int t = 0; t < SEQT; ++t) {
        if ((t & 255) == 0) {
            __syncthreads();
            for (int k = l; k < 256; k += 64) {
                const float4* src = (const float4*)(feats + (size_t)((t + k) * 32 + b) * 16);
                float4 v0 = src[0], v1 = src[1], v2 = src[2], v3 = src[3];
                float4* dst = (float4*)(fch + k * 16);
                dst[0] = v0; dst[1] = v1; dst[2] = v2; dst[3] = v3;
            }
            __syncthreads();
        }
        float best = fvloc[0] + tr[0];
        int bj = s * 4;
        #pragma unroll
        for (int m = 1; m < 4; ++m) {
            float v = fvloc[m] + tr[m];
            if (v > best) { best = v; bj = s * 4 + m; }
        }
        #pragma unroll
        for (int off = 1; off <= 2; off <<= 1) {
            float ov = __shfl_xor(best, off);
            int oj = __shfl_xor(bj, off);
            if (ov > best || (ov == best && oj < bj)) { best = ov; bj = oj; }
        }
        float fvn = best + fch[(t & 255) * 16 + i];
        if (s == 0) bp[t * 16 + i] = (unsigned char)bj;
        #pragma unroll
        for (int m = 0; m < 4; ++m) fvloc[m] = __shfl(fvn, 16 * s + 4 * m);
    }
    float bestS = fvloc[0] + trans[16 + s * 4];
    int bl = s * 4;
    #pragma unroll
    for (int m = 1; m < 4; ++m) {
        float tv = fvloc[m] + trans[16 + s * 4 + m];
        if (tv > bestS) { bestS = tv; bl = s * 4 + m; }
    }
    #pragma unroll
    for (int off = 1; off <= 2; off <<= 1) {
        float ov = __shfl_xor(bestS, off);
        int oj = __shfl_xor(bl, off);
        if (ov > bestS || (ov == bestS && oj < bl)) { bestS = ov; bl = oj; }
    }
    __syncthreads();
    if (l == 0) {
        out[b] = bestS;
        int lbl = bl;
        for (int t = SEQT - 1; t >= 0; --t) {
            path[t] = (unsigned char)lbl;
            lbl = bp[t * 16 + lbl];
        }
    }
    __syncthreads();
    for (int t = l; t < SEQT; t += 64)
        out[32 + (size_t)t * 32 + b] = (float)path[t];
}

extern "C" void kernel_launch(void* const* d_in, const int* in_sizes, int n_in,
                              void* d_out, int out_size, void* d_ws, size_t ws_size,
                              hipStream_t stream) {
    const float* source = (const float*)d_in[0];
    const float* in_W  = (const float*)d_in[1];
    const float* in_b  = (const float*)d_in[2];
    const float* Wih_f = (const float*)d_in[3];
    const float* Whh_f = (const float*)d_in[4];
    const float* b_f   = (const float*)d_in[5];
    const float* Wih_b = (const float*)d_in[6];
    const float* Whh_b = (const float*)d_in[7];
    const float* b_b   = (const float*)d_in[8];
    const float* out_W = (const float*)d_in[9];
    const float* out_b = (const float*)d_in[10];
    const float* trans = (const float*)d_in[11];
    const float* h0    = (const float*)d_in[12];
    const float* c0    = (const float*)d_in[13];
    float* out = (float*)d_out;

    char* ws = (char*)d_ws;
    unsigned short* P2      = (unsigned short*)(ws);                 // 65536*1024*2 = 134217728
    unsigned short* H       = (unsigned short*)(ws + 134217728);     // 65536*256*2  =  33554432
    float*          feats   = (float*)         (ws + 167772160);     // 65536*16*4   =   4194304
    unsigned short* Wc      = (unsigned short*)(ws + 171966464);     // 1024*512*2   =   1048576
    float*          bc      = (float*)         (ws + 173015040);     // 1024*4
    unsigned short* Whh_bf  = (unsigned short*)(ws + 173019136);     // 1024*128*2   =    262144
    unsigned short* outW_bf = (unsigned short*)(ws + 173281280);     // 16*256*2
    // total ~173.3 MB

    hipLaunchKernelGGL(k_prep_wc, dim3(128), dim3(256), 0, stream,
                       in_W, in_b, Wih_f, b_f, Wih_b, b_b, Wc, bc);
    hipLaunchKernelGGL(k_prep_misc, dim3(256), dim3(256), 0, stream,
                       Whh_f, Whh_b, out_W, Whh_bf, outW_bf);
    hipLaunchKernelGGL(k_gemm_p, dim3(4, 1024), dim3(512), 0, stream,
                       source, Wc, bc, P2);
    hipLaunchKernelGGL(k_lstm, dim3(4), dim3(512), 0, stream,
                       P2, Whh_bf, h0, c0, H);
    hipLaunchKernelGGL(k_feats, dim3(1024), dim3(256), 0, stream,
                       H, outW_bf, out_b, feats);
    hipLaunchKernelGGL(k_viterbi, dim3(32), dim3(64), 0, stream,
                       feats, trans, out);
}